// Round 13
// baseline (560.702 us; speedup 1.0000x reference)
//
#include <hip/hip_runtime.h>
#include <hip/hip_bf16.h>

// Sparse graph-attention Gumbel mask.
//
// With M = Wq^T Wk [E,E]:
//   w_ui[e] = adj*( Xu[r]·C[c] + t1[r] + u1[c] + c0 ),  C = Xi M^T
//   w_iu[e] = adj*( Xu[r]·D[c] + t2[r] + u2[c] + c0 ),  D = Xi M
//
// R13: counting-sort by (rb, c), rb = r*8/U. Edge kernel combines the two
// separately-proven wins: XCD-pinned work claiming (R12: FETCH 0.25GB) and
// the R8 linear always-load chunk loop (long branchless trips, good MLP).
// Block claims ONE 256-edge chunk of its own XCD's rb segment (single
// atomicAdd + barrier), then 16-lane groups run 16-edge linear trips; CD
// loads hit L1 within same-c runs (~6.7). Segment-max eliminated (bounded
// logits + f64 exp); s1 per-edge f64 atomics; s2 run-flush f64 atomics.

#define EMB 128
#define TAUINV 2.0f
#define NRB 8
#define CHUNKE 256
#define EPGE 16

typedef float fx4 __attribute__((ext_vector_type(4)));

__device__ __forceinline__ unsigned fkey(float f) {
    unsigned u = __float_as_uint(f);
    return (u & 0x80000000u) ? ~u : (u | 0x80000000u);
}
__device__ __forceinline__ float fdecode(unsigned u) {
    return __uint_as_float((u & 0x80000000u) ? (u ^ 0x80000000u) : ~u);
}

// ---- BIGM[k][j] (j<128: M[j][k]; j>=128: M[k][j-128]), v1, v2, c0
__global__ void k_prep(const float* __restrict__ Wq, const float* __restrict__ Wk,
                       const float* __restrict__ bq, const float* __restrict__ bk,
                       float* __restrict__ BIGM, float* __restrict__ v1,
                       float* __restrict__ v2, float* __restrict__ c0) {
    int e1 = blockIdx.x, e2 = threadIdx.x;
    float acc = 0.f;
    for (int a = 0; a < EMB; ++a) acc += Wq[a * EMB + e1] * Wk[a * EMB + e2];
    BIGM[e2 * 256 + e1] = acc;
    BIGM[e1 * 256 + 128 + e2] = acc;
    if (e2 == 0) { float s = 0.f; for (int a = 0; a < EMB; ++a) s += Wq[a * EMB + e1] * bk[a]; v1[e1] = s; }
    if (e2 == 1) { float s = 0.f; for (int a = 0; a < EMB; ++a) s += Wk[a * EMB + e1] * bq[a]; v2[e1] = s; }
    if (e1 == 0 && e2 == 2) { float s = 0.f; for (int a = 0; a < EMB; ++a) s += bq[a] * bk[a]; *c0 = s; }
}

// ---- CD[m][j] = sum_k Xi[m][k] * BIGM[k][j]
__global__ __launch_bounds__(256) void k_cd(const float* __restrict__ Xi,
                                            const float* __restrict__ BIGM,
                                            float* __restrict__ CD, int nItems) {
    __shared__ float Xs[32][EMB];
    __shared__ float Ms[32][256];
    const int t = threadIdx.x;
    const int m0 = blockIdx.x * 32;

    const float4* Xi4 = (const float4*)Xi;
    float4* Xs4 = (float4*)Xs;
    for (int idx = t; idx < 32 * 32; idx += 256) {
        int r = idx >> 5, c = idx & 31;
        int row = m0 + r;
        Xs4[idx] = (row < nItems) ? Xi4[(size_t)row * 32 + c]
                                  : make_float4(0.f, 0.f, 0.f, 0.f);
    }

    const int tc = t & 63;
    const int tr = t >> 6;
    float4 acc[8] = {};

    const float4* BG4 = (const float4*)BIGM;
    float4* Ms4 = (float4*)Ms;
    for (int kc = 0; kc < EMB; kc += 32) {
        __syncthreads();
        for (int idx = t; idx < 32 * 64; idx += 256)
            Ms4[idx] = BG4[(size_t)(kc + (idx >> 6)) * 64 + (idx & 63)];
        __syncthreads();
#pragma unroll
        for (int kk = 0; kk < 32; ++kk) {
            float4 w = Ms4[kk * 64 + tc];
#pragma unroll
            for (int i = 0; i < 8; ++i) {
                float x = Xs[tr * 8 + i][kc + kk];
                acc[i].x += x * w.x; acc[i].y += x * w.y;
                acc[i].z += x * w.z; acc[i].w += x * w.w;
            }
        }
    }
#pragma unroll
    for (int i = 0; i < 8; ++i) {
        int row = m0 + tr * 8 + i;
        if (row < nItems)
            ((float4*)(CD + (size_t)row * 256))[tc] = acc[i];
    }
}

// ---- fused: users -> t1=Xu·v1, t2=Xu·v2 ; items -> u1=Xi·v2, u2=Xi·v1
__global__ void k_rowdot2(const float* __restrict__ Xu, const float* __restrict__ Xi,
                          int U, int I,
                          const float* __restrict__ v1, const float* __restrict__ v2,
                          float* __restrict__ t1, float* __restrict__ t2,
                          float* __restrict__ u1, float* __restrict__ u2) {
    int g = blockIdx.x * 8 + (threadIdx.x >> 5);
    int l = threadIdx.x & 31;
    if (g >= U + I) return;
    const float* X = (g < U) ? (Xu + (size_t)g * EMB) : (Xi + (size_t)(g - U) * EMB);
    float4 x = ((const float4*)X)[l];
    float4 av = ((const float4*)v1)[l];
    float4 bv = ((const float4*)v2)[l];
    float pa = x.x * av.x + x.y * av.y + x.z * av.z + x.w * av.w;
    float pb = x.x * bv.x + x.y * bv.y + x.z * bv.z + x.w * bv.w;
    for (int off = 16; off; off >>= 1) { pa += __shfl_xor(pa, off); pb += __shfl_xor(pb, off); }
    if (l == 0) {
        if (g < U) { t1[g] = pa; t2[g] = pb; }
        else       { u1[g - U] = pb; u2[g - U] = pa; }
    }
}

// ================= sort machinery (key = rb*I + c) =================
__global__ void k_hist3(const int* __restrict__ rows, const int* __restrict__ cols,
                        int nnz, int U, int I, unsigned* __restrict__ cnt) {
    int i = blockIdx.x * blockDim.x + threadIdx.x, st = gridDim.x * blockDim.x;
    for (int e = i; e < nnz; e += st) {
        int rb = (int)(((long long)rows[e] * NRB) / U);
        atomicAdd(&cnt[rb * I + cols[e]], 1u);
    }
}

__global__ void k_scan1(const unsigned* __restrict__ cnt, unsigned* __restrict__ off,
                        unsigned* __restrict__ bsum, int n) {
    __shared__ unsigned sh[256];
    int i = blockIdx.x * 256 + threadIdx.x;
    unsigned v = (i < n) ? cnt[i] : 0u;
    sh[threadIdx.x] = v; __syncthreads();
    for (int d = 1; d < 256; d <<= 1) {
        unsigned t = (threadIdx.x >= d) ? sh[threadIdx.x - d] : 0u; __syncthreads();
        sh[threadIdx.x] += t; __syncthreads();
    }
    if (i < n) off[i] = sh[threadIdx.x] - v;
    if (threadIdx.x == 255) bsum[blockIdx.x] = sh[255];
}

__global__ void k_scan2(unsigned* __restrict__ bsum, int nb) {
    __shared__ unsigned sh[256];
    __shared__ unsigned carry;
    if (threadIdx.x == 0) carry = 0u;
    __syncthreads();
    for (int base = 0; base < nb; base += 256) {
        int i = base + threadIdx.x;
        unsigned v = (i < nb) ? bsum[i] : 0u;
        sh[threadIdx.x] = v; __syncthreads();
        for (int d = 1; d < 256; d <<= 1) {
            unsigned t = (threadIdx.x >= d) ? sh[threadIdx.x - d] : 0u; __syncthreads();
            sh[threadIdx.x] += t; __syncthreads();
        }
        unsigned c = carry;
        if (i < nb) bsum[i] = c + sh[threadIdx.x] - v;
        __syncthreads();
        if (threadIdx.x == 0) carry = c + sh[255];
        __syncthreads();
    }
}

__global__ void k_scan3(unsigned* __restrict__ off, const unsigned* __restrict__ bsum, int n) {
    int i = blockIdx.x * 256 + threadIdx.x;
    if (i < n) off[i] += bsum[blockIdx.x];
}

// rb segment boundaries (before scatter mutates off)
__global__ void k_bnd(const unsigned* __restrict__ off, int* __restrict__ bnd,
                      int I, int nnz) {
    int i = threadIdx.x;
    if (i < NRB) bnd[i] = (int)off[(size_t)i * I];
    if (i == NRB) bnd[NRB] = nnz;
}

// ---- scatter by (rb,c); payload = 24B {r, c, a', b1, b2, eidx}
// b' = (adj*(t[r]+u[c]+c0) - log(-log(gu))) * TAUINV
__global__ void k_scatter9(const int* __restrict__ rows, const int* __restrict__ cols,
                           const float* __restrict__ adj, const float* __restrict__ gu1,
                           const float* __restrict__ gu2,
                           const float* __restrict__ t1, const float* __restrict__ t2,
                           const float* __restrict__ u1, const float* __restrict__ u2,
                           const float* __restrict__ c0p, int nnz, int U, int I,
                           unsigned* __restrict__ off, int* __restrict__ S6) {
    const float c0 = *c0p;
    int i = blockIdx.x * blockDim.x + threadIdx.x, st = gridDim.x * blockDim.x;
    for (int e = i; e < nnz; e += st) {
        int r = rows[e], c = cols[e];
        int rb = (int)(((long long)r * NRB) / U);
        unsigned pos = atomicAdd(&off[rb * I + c], 1u);
        float a = adj[e];
        float g1 = logf(-logf(gu1[e]));   // logf: u near 1 needs relative accuracy
        float g2 = logf(-logf(gu2[e]));
        float b1 = (a * (t1[r] + u1[c] + c0) - g1) * TAUINV;
        float b2 = (a * (t2[r] + u2[c] + c0) - g2) * TAUINV;
        int* p = S6 + (size_t)pos * 6;
        *(int2*)(p)     = make_int2(r, c);
        *(int2*)(p + 2) = make_int2(__float_as_int(a * TAUINV), __float_as_int(b1));
        *(int2*)(p + 4) = make_int2(__float_as_int(b2), e);
    }
}

// ---- edge kernel: one 256-edge chunk per block, claimed from own XCD's rb
// segment (single atomic + barrier); R8-style linear always-load loop.
__global__ __launch_bounds__(256) void k_edge12(
    const float* __restrict__ Xu, const float* __restrict__ CD,
    const int* __restrict__ bnd, int* __restrict__ ctr,
    const int* __restrict__ S6,
    float2* __restrict__ L12, double* __restrict__ s1d, double* __restrict__ s2d) {
    __shared__ int2 srange;
    if (threadIdx.x == 0) {
        unsigned xcc;
        asm volatile("s_getreg_b32 %0, hwreg(HW_REG_XCC_ID)" : "=s"(xcc));
        int lo = -1, hi = -1;
        for (int t = 0; t < NRB; ++t) {
            int rb = (int)((xcc + t) & (NRB - 1));
            int b0 = bnd[rb], b1 = bnd[rb + 1];
            int g = atomicAdd(&ctr[rb], 1);
            int st = b0 + g * CHUNKE;
            if (st < b1) { lo = st; hi = (st + CHUNKE < b1) ? st + CHUNKE : b1; break; }
        }
        srange = make_int2(lo, hi);
    }
    __syncthreads();
    const int lo = srange.x, hi = srange.y;
    if (lo < 0) return;
    const int g = threadIdx.x >> 4, l = threadIdx.x & 15;
    int jb = lo + g * EPGE;
    int je = jb + EPGE; if (je > hi) je = hi;
    int cprev = -1;
    double s2acc = 0.0;
    for (int j = jb; j < je; ++j) {
        const int* sp = S6 + (size_t)j * 6;
        int2 rc = *(const int2*)sp;               // broadcast
        int2 ab = *(const int2*)(sp + 2);
        int2 be = *(const int2*)(sp + 4);
        const float4* xu = (const float4*)(Xu + (size_t)rc.x * EMB);
        const float4* cd = (const float4*)(CD + (size_t)rc.y * 256);
        float4 x0 = xu[l], x1 = xu[l + 16];
        float4 cv0 = cd[l], cv1 = cd[l + 16];
        float4 dv0 = cd[l + 32], dv1 = cd[l + 48];
        float p1 = x0.x * cv0.x + x0.y * cv0.y + x0.z * cv0.z + x0.w * cv0.w
                 + x1.x * cv1.x + x1.y * cv1.y + x1.z * cv1.z + x1.w * cv1.w;
        float p2 = x0.x * dv0.x + x0.y * dv0.y + x0.z * dv0.z + x0.w * dv0.w
                 + x1.x * dv1.x + x1.y * dv1.y + x1.z * dv1.z + x1.w * dv1.w;
#pragma unroll
        for (int off = 1; off < 16; off <<= 1) {
            p1 += __shfl_xor(p1, off);
            p2 += __shfl_xor(p2, off);
        }
        if (l == 0) {
            float aP = __int_as_float(ab.x);
            float lg1 = fmaf(aP, p1, __int_as_float(ab.y));
            float lg2 = fmaf(aP, p2, __int_as_float(be.x));
            L12[be.y] = make_float2(lg1, lg2);
            unsafeAtomicAdd(s1d + rc.x, exp((double)lg1));
            if (rc.y != cprev) {
                if (cprev >= 0) unsafeAtomicAdd(s2d + cprev, s2acc);
                cprev = rc.y; s2acc = 0.0;
            }
            s2acc += exp((double)lg2);
        }
    }
    if (l == 0 && cprev >= 0) unsafeAtomicAdd(s2d + cprev, s2acc);
}

// ---- final: coalesced; out = exp(lg)/s in double (no max needed)
__global__ void k_fin3(const int* __restrict__ rows, const int* __restrict__ cols,
                       const float2* __restrict__ L12,
                       const double* __restrict__ s1d, const double* __restrict__ s2d,
                       float* __restrict__ out, int nnz) {
    int i = blockIdx.x * blockDim.x + threadIdx.x, st = gridDim.x * blockDim.x;
    for (int e = i; e < nnz; e += st) {
        float2 lg = L12[e];
        out[e]       = (float)(exp((double)lg.x) / s1d[rows[e]]);
        out[nnz + e] = (float)(exp((double)lg.y) / s2d[cols[e]]);
    }
}

// ================= fallback (unsorted, max-based) path =================
__global__ __launch_bounds__(256) void k_edge1(
    const float* __restrict__ Xu, const float* __restrict__ CD,
    const float* __restrict__ t1, const float* __restrict__ t2,
    const float* __restrict__ u1, const float* __restrict__ u2,
    const float* __restrict__ c0p, const float* __restrict__ adj,
    const float* __restrict__ gu1, const float* __restrict__ gu2,
    const int* __restrict__ rows, const int* __restrict__ cols,
    float* __restrict__ L1, float* __restrict__ L2,
    unsigned* __restrict__ mx1, unsigned* __restrict__ mx2, int nnz) {
    const int gid = blockIdx.x * 8 + (threadIdx.x >> 5);
    const int l = threadIdx.x & 31;
    const int stride = gridDim.x * 8;
    const float c0 = *c0p;
    for (int e = gid; e < nnz; e += stride) {
        int r = rows[e], c = cols[e];
        float4 xu = ((const float4*)(Xu + (size_t)r * EMB))[l];
        const float4* cd = (const float4*)(CD + (size_t)c * 256);
        float4 cv = cd[l];
        float4 dv = cd[32 + l];
        float p1 = xu.x * cv.x + xu.y * cv.y + xu.z * cv.z + xu.w * cv.w;
        float p2 = xu.x * dv.x + xu.y * dv.y + xu.z * dv.z + xu.w * dv.w;
        for (int off = 16; off; off >>= 1) { p1 += __shfl_xor(p1, off); p2 += __shfl_xor(p2, off); }
        if (l < 2) {
            float p = (l == 0) ? p1 : p2;
            float tt = (l == 0) ? t1[r] : t2[r];
            float uu = (l == 0) ? u1[c] : u2[c];
            float g = logf(-logf(((l == 0) ? gu1 : gu2)[e]));
            float w = adj[e] * (p + tt + uu + c0);
            float lg = (w - g) * TAUINV;
            if (l == 0) { L1[e] = lg; atomicMax(mx1 + r, fkey(lg)); }
            else        { L2[e] = lg; atomicMax(mx2 + c, fkey(lg)); }
        }
    }
}

__global__ void k_sum(const int* __restrict__ rows, const int* __restrict__ cols,
                      const float* __restrict__ L1, const float* __restrict__ L2,
                      const unsigned* __restrict__ mx1, const unsigned* __restrict__ mx2,
                      float* __restrict__ s1, float* __restrict__ s2, int nnz) {
    int i = blockIdx.x * blockDim.x + threadIdx.x, st = gridDim.x * blockDim.x;
    for (int e = i; e < nnz; e += st) {
        int r = rows[e], c = cols[e];
        atomicAdd(s1 + r, expf(L1[e] - fdecode(mx1[r])));
        atomicAdd(s2 + c, expf(L2[e] - fdecode(mx2[c])));
    }
}

__global__ void k_fin2(const int* __restrict__ rows, const int* __restrict__ cols,
                       const float* __restrict__ L1, const float* __restrict__ L2,
                       const unsigned* __restrict__ mx1, const unsigned* __restrict__ mx2,
                       const float* __restrict__ s1, const float* __restrict__ s2,
                       float* __restrict__ out, int nnz) {
    int i = blockIdx.x * blockDim.x + threadIdx.x, st = gridDim.x * blockDim.x;
    for (int e = i; e < nnz; e += st) {
        int r = rows[e], c = cols[e];
        out[e]       = expf(L1[e] - fdecode(mx1[r])) / s1[r];
        out[nnz + e] = expf(L2[e] - fdecode(mx2[c])) / s2[c];
    }
}

extern "C" void kernel_launch(void* const* d_in, const int* in_sizes, int n_in,
                              void* d_out, int out_size, void* d_ws, size_t ws_size,
                              hipStream_t stream) {
    const float* Xu  = (const float*)d_in[0];
    const float* Xi  = (const float*)d_in[1];
    const float* Wq  = (const float*)d_in[2];
    const float* bq  = (const float*)d_in[3];
    const float* Wk  = (const float*)d_in[4];
    const float* bk  = (const float*)d_in[5];
    const float* adj = (const float*)d_in[6];
    const float* gu1 = (const float*)d_in[7];
    const float* gu2 = (const float*)d_in[8];
    const int* rows  = (const int*)d_in[9];
    const int* cols  = (const int*)d_in[10];
    float* out = (float*)d_out;

    const int U   = in_sizes[0] / EMB;
    const int I   = in_sizes[1] / EMB;
    const int nnz = in_sizes[6];
    const int NB  = NRB * I;
    const int numB1 = (NB + 255) / 256;

    char* w = (char*)d_ws;
    size_t off_b = 0;
    auto alloc = [&](size_t bytes) {
        char* p = w + off_b;
        off_b += (bytes + 15) & ~(size_t)15;
        return p;
    };

    float* BIGM = (float*)alloc(32768 * 4);
    float* v1   = (float*)alloc(128 * 4);
    float* v2   = (float*)alloc(128 * 4);
    float* c0   = (float*)alloc(64 * 4);
    float* t1   = (float*)alloc((size_t)U * 4);
    float* t2   = (float*)alloc((size_t)U * 4);
    float* u1   = (float*)alloc((size_t)I * 4);
    float* u2   = (float*)alloc((size_t)I * 4);
    float* CD   = (float*)alloc((size_t)I * 256 * 4);
    float2* L12 = (float2*)alloc((size_t)nnz * 8);
    size_t base_need = off_b;
    // sorted-path extras: s1d, s2d, cnt, ctr contiguous -> single memset
    double* s1d   = (double*)alloc((size_t)U * 8);
    double* s2d   = (double*)alloc((size_t)I * 8);
    unsigned* cnt = (unsigned*)alloc((size_t)NB * 4);
    int* ctr      = (int*)alloc(16 * 4);
    unsigned* offp = (unsigned*)alloc((size_t)NB * 4);
    unsigned* bsum = (unsigned*)alloc(((size_t)numB1 + 8) * 4);
    int* bnd = (int*)alloc(16 * 4);
    int* S6 = (int*)alloc((size_t)nnz * 24);
    size_t sorted_need = off_b;
    // fallback extras
    unsigned* mx1 = (unsigned*)alloc((size_t)U * 4);
    unsigned* mx2 = (unsigned*)alloc((size_t)I * 4);
    float* s1f  = (float*)alloc((size_t)U * 4);
    float* s2f  = (float*)alloc((size_t)I * 4);
    size_t fallback_need = off_b;

    const bool use_sorted = (sorted_need <= ws_size);
    if (!use_sorted && fallback_need > ws_size) return;

    k_prep<<<128, 128, 0, stream>>>(Wq, Wk, bq, bk, BIGM, v1, v2, c0);
    k_cd<<<(I + 31) / 32, 256, 0, stream>>>(Xi, BIGM, CD, I);
    k_rowdot2<<<(U + I + 7) / 8, 256, 0, stream>>>(Xu, Xi, U, I, v1, v2, t1, t2, u1, u2);

    if (use_sorted) {
        // zero s1d + s2d + cnt + ctr in one contiguous memset
        (void)hipMemsetAsync(s1d, 0,
                             (size_t)U * 8 + (size_t)I * 8 + (size_t)NB * 4 + 64,
                             stream);
        k_hist3<<<2048, 256, 0, stream>>>(rows, cols, nnz, U, I, cnt);
        k_scan1<<<numB1, 256, 0, stream>>>(cnt, offp, bsum, NB);
        k_scan2<<<1, 256, 0, stream>>>(bsum, numB1);
        k_scan3<<<numB1, 256, 0, stream>>>(offp, bsum, NB);
        k_bnd<<<1, 64, 0, stream>>>(offp, bnd, I, nnz);
        k_scatter9<<<2048, 256, 0, stream>>>(rows, cols, adj, gu1, gu2,
                                             t1, t2, u1, u2, c0, nnz, U, I,
                                             offp, S6);
        const int nblk = (nnz + CHUNKE - 1) / CHUNKE + NRB;
        k_edge12<<<nblk, 256, 0, stream>>>(Xu, CD, bnd, ctr, S6, L12, s1d, s2d);
        k_fin3<<<2048, 256, 0, stream>>>(rows, cols, L12, s1d, s2d, out, nnz);
    } else {
        float* L1 = (float*)L12;
        float* L2 = L1 + nnz;
        (void)hipMemsetAsync(mx1, 0, (size_t)(2 * (U + I)) * 4, stream);
        k_edge1<<<4096, 256, 0, stream>>>(Xu, CD, t1, t2, u1, u2, c0, adj, gu1, gu2,
                                          rows, cols, L1, L2, mx1, mx2, nnz);
        k_sum<<<2048, 256, 0, stream>>>(rows, cols, L1, L2, mx1, mx2, s1f, s2f, nnz);
        k_fin2<<<2048, 256, 0, stream>>>(rows, cols, L1, L2, mx1, mx2, s1f, s2f,
                                         out, nnz);
    }
}

// Round 14
// 407.162 us; speedup vs baseline: 1.3771x; 1.3771x over previous
//
#include <hip/hip_runtime.h>
#include <hip/hip_bf16.h>

// Sparse graph-attention Gumbel mask.
//
// With M = Wq^T Wk [E,E]:
//   w_ui[e] = adj*( Xu[r]·C[c] + t1[r] + u1[c] + c0 ),  C = Xi M^T
//   w_iu[e] = adj*( Xu[r]·D[c] + t2[r] + u2[c] + c0 ),  D = Xi M
//
// R14 = R10 (best: c-sort, bin-per-16-lane-group, no-max f64 softmax)
// + fast exp (exp2f + v_ldexp_f64: ~7 ops vs ~35 for libm f64 exp)
// + tail split across lanes 0/1 (2x parallelism on the per-edge tail)
// + pure-f32 final pass via precomputed log2(sum) (k_ls)
// + float2-packed t/u bias tables (halves scatter gathers).

#define EMB 128
#define TAUINV 2.0f
#define LOG2E 1.44269504f

__device__ __forceinline__ unsigned fkey(float f) {
    unsigned u = __float_as_uint(f);
    return (u & 0x80000000u) ? ~u : (u | 0x80000000u);
}
__device__ __forceinline__ float fdecode(unsigned u) {
    return __uint_as_float((u & 0x80000000u) ? (u ^ 0x80000000u) : ~u);
}

// exp(lg) as double without overflow: exp2f on the fraction, ldexp for the
// integer part (v_exp_f32 + v_ldexp_f64; rel err ~1.5e-5, fine vs 2e-2 tol).
__device__ __forceinline__ double dexp_fast(float lg) {
    float t = lg * LOG2E;
    float kf = floorf(t);
    float f = exp2f(t - kf);
    return ldexp((double)f, (int)kf);
}

// ---- BIGM[k][j] (j<128: M[j][k]; j>=128: M[k][j-128]), v1, v2, c0
__global__ void k_prep(const float* __restrict__ Wq, const float* __restrict__ Wk,
                       const float* __restrict__ bq, const float* __restrict__ bk,
                       float* __restrict__ BIGM, float* __restrict__ v1,
                       float* __restrict__ v2, float* __restrict__ c0) {
    int e1 = blockIdx.x, e2 = threadIdx.x;
    float acc = 0.f;
    for (int a = 0; a < EMB; ++a) acc += Wq[a * EMB + e1] * Wk[a * EMB + e2];
    BIGM[e2 * 256 + e1] = acc;
    BIGM[e1 * 256 + 128 + e2] = acc;
    if (e2 == 0) { float s = 0.f; for (int a = 0; a < EMB; ++a) s += Wq[a * EMB + e1] * bk[a]; v1[e1] = s; }
    if (e2 == 1) { float s = 0.f; for (int a = 0; a < EMB; ++a) s += Wk[a * EMB + e1] * bq[a]; v2[e1] = s; }
    if (e1 == 0 && e2 == 2) { float s = 0.f; for (int a = 0; a < EMB; ++a) s += bq[a] * bk[a]; *c0 = s; }
}

// ---- CD[m][j] = sum_k Xi[m][k] * BIGM[k][j]
__global__ __launch_bounds__(256) void k_cd(const float* __restrict__ Xi,
                                            const float* __restrict__ BIGM,
                                            float* __restrict__ CD, int nItems) {
    __shared__ float Xs[32][EMB];
    __shared__ float Ms[32][256];
    const int t = threadIdx.x;
    const int m0 = blockIdx.x * 32;

    const float4* Xi4 = (const float4*)Xi;
    float4* Xs4 = (float4*)Xs;
    for (int idx = t; idx < 32 * 32; idx += 256) {
        int r = idx >> 5, c = idx & 31;
        int row = m0 + r;
        Xs4[idx] = (row < nItems) ? Xi4[(size_t)row * 32 + c]
                                  : make_float4(0.f, 0.f, 0.f, 0.f);
    }

    const int tc = t & 63;
    const int tr = t >> 6;
    float4 acc[8] = {};

    const float4* BG4 = (const float4*)BIGM;
    float4* Ms4 = (float4*)Ms;
    for (int kc = 0; kc < EMB; kc += 32) {
        __syncthreads();
        for (int idx = t; idx < 32 * 64; idx += 256)
            Ms4[idx] = BG4[(size_t)(kc + (idx >> 6)) * 64 + (idx & 63)];
        __syncthreads();
#pragma unroll
        for (int kk = 0; kk < 32; ++kk) {
            float4 w = Ms4[kk * 64 + tc];
#pragma unroll
            for (int i = 0; i < 8; ++i) {
                float x = Xs[tr * 8 + i][kc + kk];
                acc[i].x += x * w.x; acc[i].y += x * w.y;
                acc[i].z += x * w.z; acc[i].w += x * w.w;
            }
        }
    }
#pragma unroll
    for (int i = 0; i < 8; ++i) {
        int row = m0 + tr * 8 + i;
        if (row < nItems)
            ((float4*)(CD + (size_t)row * 256))[tc] = acc[i];
    }
}

// ---- fused rowdots, packed: t12[r]={Xu.v1,Xu.v2}, u12[c]={Xi.v2,Xi.v1}
__global__ void k_rowdot2(const float* __restrict__ Xu, const float* __restrict__ Xi,
                          int U, int I,
                          const float* __restrict__ v1, const float* __restrict__ v2,
                          float2* __restrict__ t12, float2* __restrict__ u12) {
    int g = blockIdx.x * 8 + (threadIdx.x >> 5);
    int l = threadIdx.x & 31;
    if (g >= U + I) return;
    const float* X = (g < U) ? (Xu + (size_t)g * EMB) : (Xi + (size_t)(g - U) * EMB);
    float4 x = ((const float4*)X)[l];
    float4 av = ((const float4*)v1)[l];
    float4 bv = ((const float4*)v2)[l];
    float pa = x.x * av.x + x.y * av.y + x.z * av.z + x.w * av.w;
    float pb = x.x * bv.x + x.y * bv.y + x.z * bv.z + x.w * bv.w;
    for (int off = 16; off; off >>= 1) { pa += __shfl_xor(pa, off); pb += __shfl_xor(pb, off); }
    if (l == 0) {
        if (g < U) t12[g] = make_float2(pa, pb);
        else       u12[g - U] = make_float2(pb, pa);
    }
}

// ================= sort machinery (key = c) =================
__global__ void k_hist2(const int* __restrict__ cols, int nnz,
                        unsigned* __restrict__ cnt) {
    int i = blockIdx.x * blockDim.x + threadIdx.x, st = gridDim.x * blockDim.x;
    for (int e = i; e < nnz; e += st) atomicAdd(&cnt[cols[e]], 1u);
}

__global__ void k_scan1(const unsigned* __restrict__ cnt, unsigned* __restrict__ off,
                        unsigned* __restrict__ bsum, int n) {
    __shared__ unsigned sh[256];
    int i = blockIdx.x * 256 + threadIdx.x;
    unsigned v = (i < n) ? cnt[i] : 0u;
    sh[threadIdx.x] = v; __syncthreads();
    for (int d = 1; d < 256; d <<= 1) {
        unsigned t = (threadIdx.x >= d) ? sh[threadIdx.x - d] : 0u; __syncthreads();
        sh[threadIdx.x] += t; __syncthreads();
    }
    if (i < n) off[i] = sh[threadIdx.x] - v;
    if (threadIdx.x == 255) bsum[blockIdx.x] = sh[255];
}

__global__ void k_scan2(unsigned* __restrict__ bsum, int nb) {
    __shared__ unsigned sh[256];
    __shared__ unsigned carry;
    if (threadIdx.x == 0) carry = 0u;
    __syncthreads();
    for (int base = 0; base < nb; base += 256) {
        int i = base + threadIdx.x;
        unsigned v = (i < nb) ? bsum[i] : 0u;
        sh[threadIdx.x] = v; __syncthreads();
        for (int d = 1; d < 256; d <<= 1) {
            unsigned t = (threadIdx.x >= d) ? sh[threadIdx.x - d] : 0u; __syncthreads();
            sh[threadIdx.x] += t; __syncthreads();
        }
        unsigned c = carry;
        if (i < nb) bsum[i] = c + sh[threadIdx.x] - v;
        __syncthreads();
        if (threadIdx.x == 0) carry = c + sh[255];
        __syncthreads();
    }
}

__global__ void k_scan3(unsigned* __restrict__ off, const unsigned* __restrict__ bsum, int n) {
    int i = blockIdx.x * 256 + threadIdx.x;
    if (i < n) off[i] += bsum[blockIdx.x];
}

// ---- scatter by c; payload = 24B {r, eidx, a', b1, b2, pad}
// b' = (adj*(t[r]+u[c]+c0) - log(-log(gu))) * TAUINV
__global__ void k_scatter7(const int* __restrict__ rows, const int* __restrict__ cols,
                           const float* __restrict__ adj, const float* __restrict__ gu1,
                           const float* __restrict__ gu2,
                           const float2* __restrict__ t12, const float2* __restrict__ u12,
                           const float* __restrict__ c0p, int nnz,
                           unsigned* __restrict__ off, int* __restrict__ S6) {
    const float c0 = *c0p;
    int i = blockIdx.x * blockDim.x + threadIdx.x, st = gridDim.x * blockDim.x;
    for (int e = i; e < nnz; e += st) {
        int r = rows[e], c = cols[e];
        unsigned pos = atomicAdd(&off[c], 1u);
        float a = adj[e];
        float g1 = logf(-logf(gu1[e]));   // logf: u near 1 needs relative accuracy
        float g2 = logf(-logf(gu2[e]));
        float2 tt = t12[r];
        float2 uu = u12[c];
        float b1 = (a * (tt.x + uu.x + c0) - g1) * TAUINV;
        float b2 = (a * (tt.y + uu.y + c0) - g2) * TAUINV;
        int* p = S6 + (size_t)pos * 6;
        *(int2*)(p)     = make_int2(r, e);
        *(int2*)(p + 2) = make_int2(__float_as_int(a * TAUINV), __float_as_int(b1));
        *(int2*)(p + 4) = make_int2(__float_as_int(b2), 0);
    }
}

// ---- edge kernel: one bin per 16-lane group; CD register-held; tail split
// across lanes 0/1 with fast exp; s2 plain store (unique c per group).
__global__ __launch_bounds__(256) void k_edge10(
    const float* __restrict__ Xu, const float* __restrict__ CD,
    const unsigned* __restrict__ offp, const int* __restrict__ S6,
    float2* __restrict__ L12, double* __restrict__ s1d, double* __restrict__ s2d,
    int I) {
    const int g = threadIdx.x >> 4, l = threadIdx.x & 15;
    const int c = blockIdx.x * 16 + g;
    if (c >= I) return;
    const unsigned lo = (c == 0) ? 0u : offp[c - 1];
    const unsigned hi = offp[c];
    if (lo >= hi) return;
    const float4* cd = (const float4*)(CD + (size_t)c * 256);
    const float4 cv0 = cd[l], cv1 = cd[l + 16];
    const float4 dv0 = cd[l + 32], dv1 = cd[l + 48];
    double s2acc = 0.0;
    for (unsigned j = lo; j < hi; ++j) {
        const int* sp = S6 + (size_t)j * 6;
        int2 re = *(const int2*)sp;               // broadcast
        int2 ab = *(const int2*)(sp + 2);
        int2 b2p = *(const int2*)(sp + 4);
        const float4* xu = (const float4*)(Xu + (size_t)re.x * EMB);
        float4 x0 = xu[l], x1 = xu[l + 16];
        float p1 = x0.x * cv0.x + x0.y * cv0.y + x0.z * cv0.z + x0.w * cv0.w
                 + x1.x * cv1.x + x1.y * cv1.y + x1.z * cv1.z + x1.w * cv1.w;
        float p2 = x0.x * dv0.x + x0.y * dv0.y + x0.z * dv0.z + x0.w * dv0.w
                 + x1.x * dv1.x + x1.y * dv1.y + x1.z * dv1.z + x1.w * dv1.w;
#pragma unroll
        for (int off = 1; off < 16; off <<= 1) {
            p1 += __shfl_xor(p1, off);
            p2 += __shfl_xor(p2, off);
        }
        if (l < 2) {
            float aP = __int_as_float(ab.x);
            float bP = __int_as_float((l == 0) ? ab.y : b2p.x);
            float lg = fmaf(aP, (l == 0) ? p1 : p2, bP);
            double ev = dexp_fast(lg);
            ((float*)(L12 + re.y))[l] = lg;       // lane0 -> .x, lane1 -> .y
            if (l == 0) unsafeAtomicAdd(s1d + re.x, ev);
            else        s2acc += ev;
        }
    }
    if (l == 1) s2d[c] = s2acc;
}

// ---- ls = log2(sum) per row/col (float); frexp + log2f (cheap, 80K thr)
__global__ void k_ls(const double* __restrict__ s1d, const double* __restrict__ s2d,
                     float* __restrict__ ls1, float* __restrict__ ls2, int U, int I) {
    int i = blockIdx.x * blockDim.x + threadIdx.x;
    if (i >= U + I) return;
    double s = (i < U) ? s1d[i] : s2d[i - U];
    int ex;
    double m = frexp(s, &ex);
    float l2 = log2f((float)m) + (float)ex;
    if (i < U) ls1[i] = l2; else ls2[i - U] = l2;
}

// ---- final: pure f32, coalesced; out = exp2(lg*log2e - log2(sum))
__global__ void k_fin4(const int* __restrict__ rows, const int* __restrict__ cols,
                       const float2* __restrict__ L12,
                       const float* __restrict__ ls1, const float* __restrict__ ls2,
                       float* __restrict__ out, int nnz) {
    int i = blockIdx.x * blockDim.x + threadIdx.x, st = gridDim.x * blockDim.x;
    for (int e = i; e < nnz; e += st) {
        float2 lg = L12[e];
        out[e]       = exp2f(fmaf(lg.x, LOG2E, -ls1[rows[e]]));
        out[nnz + e] = exp2f(fmaf(lg.y, LOG2E, -ls2[cols[e]]));
    }
}

// ================= fallback (unsorted, max-based) path =================
__global__ __launch_bounds__(256) void k_edge1(
    const float* __restrict__ Xu, const float* __restrict__ CD,
    const float2* __restrict__ t12, const float2* __restrict__ u12,
    const float* __restrict__ c0p, const float* __restrict__ adj,
    const float* __restrict__ gu1, const float* __restrict__ gu2,
    const int* __restrict__ rows, const int* __restrict__ cols,
    float* __restrict__ L1, float* __restrict__ L2,
    unsigned* __restrict__ mx1, unsigned* __restrict__ mx2, int nnz) {
    const int gid = blockIdx.x * 8 + (threadIdx.x >> 5);
    const int l = threadIdx.x & 31;
    const int stride = gridDim.x * 8;
    const float c0 = *c0p;
    for (int e = gid; e < nnz; e += stride) {
        int r = rows[e], c = cols[e];
        float4 xu = ((const float4*)(Xu + (size_t)r * EMB))[l];
        const float4* cd = (const float4*)(CD + (size_t)c * 256);
        float4 cv = cd[l];
        float4 dv = cd[32 + l];
        float p1 = xu.x * cv.x + xu.y * cv.y + xu.z * cv.z + xu.w * cv.w;
        float p2 = xu.x * dv.x + xu.y * dv.y + xu.z * dv.z + xu.w * dv.w;
        for (int off = 16; off; off >>= 1) { p1 += __shfl_xor(p1, off); p2 += __shfl_xor(p2, off); }
        if (l < 2) {
            float p = (l == 0) ? p1 : p2;
            float2 tt = t12[r];
            float2 uu = u12[c];
            float tb = (l == 0) ? tt.x : tt.y;
            float ub = (l == 0) ? uu.x : uu.y;
            float g = logf(-logf(((l == 0) ? gu1 : gu2)[e]));
            float w = adj[e] * (p + tb + ub + c0);
            float lg = (w - g) * TAUINV;
            if (l == 0) { L1[e] = lg; atomicMax(mx1 + r, fkey(lg)); }
            else        { L2[e] = lg; atomicMax(mx2 + c, fkey(lg)); }
        }
    }
}

__global__ void k_sum(const int* __restrict__ rows, const int* __restrict__ cols,
                      const float* __restrict__ L1, const float* __restrict__ L2,
                      const unsigned* __restrict__ mx1, const unsigned* __restrict__ mx2,
                      float* __restrict__ s1, float* __restrict__ s2, int nnz) {
    int i = blockIdx.x * blockDim.x + threadIdx.x, st = gridDim.x * blockDim.x;
    for (int e = i; e < nnz; e += st) {
        int r = rows[e], c = cols[e];
        atomicAdd(s1 + r, expf(L1[e] - fdecode(mx1[r])));
        atomicAdd(s2 + c, expf(L2[e] - fdecode(mx2[c])));
    }
}

__global__ void k_fin2(const int* __restrict__ rows, const int* __restrict__ cols,
                       const float* __restrict__ L1, const float* __restrict__ L2,
                       const unsigned* __restrict__ mx1, const unsigned* __restrict__ mx2,
                       const float* __restrict__ s1, const float* __restrict__ s2,
                       float* __restrict__ out, int nnz) {
    int i = blockIdx.x * blockDim.x + threadIdx.x, st = gridDim.x * blockDim.x;
    for (int e = i; e < nnz; e += st) {
        int r = rows[e], c = cols[e];
        out[e]       = expf(L1[e] - fdecode(mx1[r])) / s1[r];
        out[nnz + e] = expf(L2[e] - fdecode(mx2[c])) / s2[c];
    }
}

extern "C" void kernel_launch(void* const* d_in, const int* in_sizes, int n_in,
                              void* d_out, int out_size, void* d_ws, size_t ws_size,
                              hipStream_t stream) {
    const float* Xu  = (const float*)d_in[0];
    const float* Xi  = (const float*)d_in[1];
    const float* Wq  = (const float*)d_in[2];
    const float* bq  = (const float*)d_in[3];
    const float* Wk  = (const float*)d_in[4];
    const float* bk  = (const float*)d_in[5];
    const float* adj = (const float*)d_in[6];
    const float* gu1 = (const float*)d_in[7];
    const float* gu2 = (const float*)d_in[8];
    const int* rows  = (const int*)d_in[9];
    const int* cols  = (const int*)d_in[10];
    float* out = (float*)d_out;

    const int U   = in_sizes[0] / EMB;
    const int I   = in_sizes[1] / EMB;
    const int nnz = in_sizes[6];
    const int numB1 = (I + 255) / 256;

    char* w = (char*)d_ws;
    size_t off_b = 0;
    auto alloc = [&](size_t bytes) {
        char* p = w + off_b;
        off_b += (bytes + 15) & ~(size_t)15;
        return p;
    };

    float* BIGM = (float*)alloc(32768 * 4);
    float* v1   = (float*)alloc(128 * 4);
    float* v2   = (float*)alloc(128 * 4);
    float* c0   = (float*)alloc(64 * 4);
    float2* t12 = (float2*)alloc((size_t)U * 8);
    float2* u12 = (float2*)alloc((size_t)I * 8);
    float* CD   = (float*)alloc((size_t)I * 256 * 4);
    float2* L12 = (float2*)alloc((size_t)nnz * 8);
    size_t base_need = off_b;
    // sorted-path extras: s1d + cnt contiguous -> single memset
    double* s1d   = (double*)alloc((size_t)U * 8);
    unsigned* cnt = (unsigned*)alloc((size_t)I * 4);
    double* s2d   = (double*)alloc((size_t)I * 8);
    float* ls1    = (float*)alloc((size_t)U * 4);
    float* ls2    = (float*)alloc((size_t)I * 4);
    unsigned* offp = (unsigned*)alloc((size_t)I * 4);
    unsigned* bsum = (unsigned*)alloc(((size_t)numB1 + 8) * 4);
    int* S6 = (int*)alloc((size_t)nnz * 24);
    size_t sorted_need = off_b;
    // fallback extras
    unsigned* mx1 = (unsigned*)alloc((size_t)U * 4);
    unsigned* mx2 = (unsigned*)alloc((size_t)I * 4);
    float* s1f  = (float*)alloc((size_t)U * 4);
    float* s2f  = (float*)alloc((size_t)I * 4);
    size_t fallback_need = off_b;

    const bool use_sorted = (sorted_need <= ws_size);
    if (!use_sorted && fallback_need > ws_size) return;

    k_prep<<<128, 128, 0, stream>>>(Wq, Wk, bq, bk, BIGM, v1, v2, c0);
    k_cd<<<(I + 31) / 32, 256, 0, stream>>>(Xi, BIGM, CD, I);
    k_rowdot2<<<(U + I + 7) / 8, 256, 0, stream>>>(Xu, Xi, U, I, v1, v2, t12, u12);

    if (use_sorted) {
        // zero s1d (U doubles) + cnt (I uints) in one contiguous memset
        (void)hipMemsetAsync(s1d, 0, (size_t)U * 8 + (size_t)I * 4, stream);
        k_hist2<<<2048, 256, 0, stream>>>(cols, nnz, cnt);
        k_scan1<<<numB1, 256, 0, stream>>>(cnt, offp, bsum, I);
        k_scan2<<<1, 256, 0, stream>>>(bsum, numB1);
        k_scan3<<<numB1, 256, 0, stream>>>(offp, bsum, I);
        k_scatter7<<<2048, 256, 0, stream>>>(rows, cols, adj, gu1, gu2,
                                             t12, u12, c0, nnz, offp, S6);
        k_edge10<<<(I + 15) / 16, 256, 0, stream>>>(Xu, CD, offp, S6, L12,
                                                    s1d, s2d, I);
        k_ls<<<(U + I + 255) / 256, 256, 0, stream>>>(s1d, s2d, ls1, ls2, U, I);
        k_fin4<<<2048, 256, 0, stream>>>(rows, cols, L12, ls1, ls2, out, nnz);
    } else {
        float* L1 = (float*)L12;
        float* L2 = L1 + nnz;
        (void)hipMemsetAsync(mx1, 0, (size_t)(2 * (U + I)) * 4, stream);
        k_edge1<<<4096, 256, 0, stream>>>(Xu, CD, t12, u12, c0, adj, gu1, gu2,
                                          rows, cols, L1, L2, mx1, mx2, nnz);
        k_sum<<<2048, 256, 0, stream>>>(rows, cols, L1, L2, mx1, mx2, s1f, s2f, nnz);
        k_fin2<<<2048, 256, 0, stream>>>(rows, cols, L1, L2, mx1, mx2, s1f, s2f,
                                         out, nnz);
    }
}